// Round 18
// baseline (123.274 us; speedup 1.0000x reference)
//
#include <hip/hip_runtime.h>
#include <hip/hip_bf16.h>

// Problem constants (Whisper-style MHA): B=2, S=2048, D=1024, H=16, hd=64
#define BB 2
#define SS 2048
#define DD 1024
#define HH 16
#define HD 64
#define QKSCALE 0.35355339059327373f   // 64^-0.25
// 64^-0.25 * sqrt(log2(e)) : folds exp->exp2 domain change into q,k projections
#define QKSCALE_E2 0.42466090144f
#define NEGBIG (-1e9f)

using u16 = unsigned short;
typedef __attribute__((ext_vector_type(8))) short short8;     // 8 bf16 = 4 VGPR
typedef __attribute__((ext_vector_type(4))) float floatx4;    // MFMA acc
typedef __attribute__((ext_vector_type(4))) unsigned short ushort4v;

#define GLOBAL_AS __attribute__((address_space(1)))
#define LDS_AS __attribute__((address_space(3)))

__device__ __forceinline__ u16 f2b(float f) {          // RNE f32->bf16
  union { float f; unsigned u; } v; v.f = f;
  return (u16)((v.u + 0x7fffu + ((v.u >> 16) & 1u)) >> 16);
}

__device__ __forceinline__ u16 bconv(float f) {        // via HW cvt (fuses to cvt_pk)
  union { __hip_bfloat16 h; u16 u; } cv;
  cv.h = __float2bfloat16(f);
  return cv.u;
}

__device__ __forceinline__ float ex2(float f) {        // raw v_exp_f32 (2^x)
  return __builtin_amdgcn_exp2f(f);
}

__device__ __forceinline__ floatx4 vmax4(floatx4 a, floatx4 b) {
  return (floatx4){fmaxf(a[0], b[0]), fmaxf(a[1], b[1]),
                   fmaxf(a[2], b[2]), fmaxf(a[3], b[3])};
}

__device__ __forceinline__ void gload_lds16(const void* g, void* l) {
  __builtin_amdgcn_global_load_lds((GLOBAL_AS void*)(g), (LDS_AS void*)(l), 16, 0, 0);
}

// ---------------- elementwise f32 -> bf16 ----------------
__global__ __launch_bounds__(256) void cvt_bf16x4(const float4* __restrict__ src,
                                                  ushort4v* __restrict__ dst, int n4) {
  int i = blockIdx.x * 256 + threadIdx.x;
  if (i >= n4) return;
  float4 f = src[i];
  ushort4v o = { f2b(f.x), f2b(f.y), f2b(f.z), f2b(f.w) };
  dst[i] = o;
}

// ------------- weight transpose+convert: W[K][N] f32 -> Wt[N][K] bf16 (4 weights) -------------
__global__ __launch_bounds__(256) void transpose_w(const float* __restrict__ s0,
                                                   const float* __restrict__ s1,
                                                   const float* __restrict__ s2,
                                                   const float* __restrict__ s3,
                                                   u16* __restrict__ dst) {
  __shared__ float tile[32][33];
  const float* src = (blockIdx.z == 0) ? s0 : (blockIdx.z == 1) ? s1
                   : (blockIdx.z == 2) ? s2 : s3;
  u16* d = dst + (size_t)blockIdx.z * 1024 * 1024;
  int c0 = blockIdx.x * 32, r0 = blockIdx.y * 32;
  int tx = threadIdx.x, ty = threadIdx.y;     // block (32,8)
#pragma unroll
  for (int i = 0; i < 4; ++i)
    tile[ty + i * 8][tx] = src[(size_t)(r0 + ty + i * 8) * 1024 + c0 + tx];
  __syncthreads();
#pragma unroll
  for (int i = 0; i < 4; ++i)
    d[(size_t)(c0 + ty + i * 8) * 1024 + r0 + tx] = f2b(tile[tx][ty + i * 8]);
}

// ------------- out-proj GEMM: 64x128 tile, BK=64, dbuf prefetch, XCD swizzle -------------
template <typename OutT>
__global__ __launch_bounds__(256, 3)
void gemm_bt(const u16* __restrict__ A, const u16* __restrict__ Bt,
             OutT* __restrict__ C, const float* __restrict__ bias,
             float scale, int M, int N, int K) {
  const int tid = threadIdx.x;
  const int lane = tid & 63;
  const int w = tid >> 6;
  const int id = (int)blockIdx.x;
  const int swz = (id & 7) * 64 + (id >> 3);
  const int m0 = (swz & 63) * 64;
  const int n0 = (swz >> 6) * 128;
  __shared__ u16 As[2][64 * 64];     // 8KB per buf
  __shared__ u16 Bs[2][128 * 64];    // 16KB per buf
  floatx4 acc[2][4];
#pragma unroll
  for (int i = 0; i < 2; ++i)
#pragma unroll
    for (int j = 0; j < 4; ++j) acc[i][j] = (floatx4){0.f, 0.f, 0.f, 0.f};

  const int wr = (w >> 1) * 32;
  const int wc = (w & 1) * 64;
  const int g = lane >> 4;
  const int lr = lane & 15;
  const size_t strideA = (size_t)K * 2;

  auto stage = [&](int k0, int buf) {
#pragma unroll
    for (int p = 0; p < 2; ++p) {    // A: 8KB
      int L = tid * 16 + p * 4096;
      int row = L >> 7;
      int cb = (L ^ ((row & 7) << 4)) & 127;
      gload_lds16((const char*)A + (size_t)(m0 + row) * strideA + k0 * 2 + cb,
                  (char*)As[buf] + p * 4096 + w * 1024);
    }
#pragma unroll
    for (int p = 0; p < 4; ++p) {    // B: 16KB
      int L = tid * 16 + p * 4096;
      int row = L >> 7;
      int cb = (L ^ ((row & 7) << 4)) & 127;
      gload_lds16((const char*)Bt + (size_t)(n0 + row) * strideA + k0 * 2 + cb,
                  (char*)Bs[buf] + p * 4096 + w * 1024);
    }
  };

  const int nsteps = K >> 6;
  stage(0, 0);
  for (int t = 0; t < nsteps; ++t) {
    const int buf = t & 1;
    __syncthreads();                       // drains stage(t); guards buf reuse
    if (t + 1 < nsteps) stage((t + 1) << 6, buf ^ 1);
    const u16* as = As[buf];
    const u16* bs = Bs[buf];
#pragma unroll
    for (int ks = 0; ks < 2; ++ks) {
      short8 af[2], bf[4];
      const int c0 = ks * 32 + g * 8;
#pragma unroll
      for (int mi = 0; mi < 2; ++mi) {
        int row = wr + mi * 16 + lr;
        af[mi] = *(const short8*)(as + row * 64 + (c0 ^ ((row & 7) << 3)));
      }
#pragma unroll
      for (int ni = 0; ni < 4; ++ni) {
        int row = wc + ni * 16 + lr;
        bf[ni] = *(const short8*)(bs + row * 64 + (c0 ^ ((row & 7) << 3)));
      }
      __builtin_amdgcn_s_setprio(1);
#pragma unroll
      for (int mi = 0; mi < 2; ++mi)
#pragma unroll
        for (int ni = 0; ni < 4; ++ni)
          acc[mi][ni] = __builtin_amdgcn_mfma_f32_16x16x32_bf16(af[mi], bf[ni],
                                                                acc[mi][ni], 0, 0, 0);
      __builtin_amdgcn_s_setprio(0);
    }
  }
#pragma unroll
  for (int ni = 0; ni < 4; ++ni) {
    int col = n0 + wc + ni * 16 + lr;
    float bvv = bias ? bias[col] : 0.f;
#pragma unroll
    for (int mi = 0; mi < 2; ++mi) {
#pragma unroll
      for (int r = 0; r < 4; ++r) {
        int rowg = m0 + wr + mi * 16 + g * 4 + r;
        float val = (acc[mi][ni][r] + bvv) * scale;
        if constexpr (sizeof(OutT) == 4) C[(size_t)rowg * N + col] = val;
        else C[(size_t)rowg * N + col] = (OutT)f2b(val);
      }
    }
  }
}

// ------------- fused QKV GEMM: 128x128 tile, BK=32 dbuf, XCD swizzle -------------
// seg 0/1 (q,k): coalesced store via per-wave LDS bounce.
// seg 2 (v): direct transposed store into vtb[b*1024+d][s] -> transpose_v eliminated.
__global__ __launch_bounds__(256, 4)
void gemm_qkv(const u16* __restrict__ A, const u16* __restrict__ Wt3,
              u16* __restrict__ Out3, u16* __restrict__ Vt,
              const float* __restrict__ bq, const float* __restrict__ bv) {
  const int id = (int)blockIdx.x;
  const int swz = (id & 7) * 96 + (id >> 3);
  const int bx = swz & 31;
  const int rest = swz >> 5;
  const int by = rest & 7;
  const int seg = rest >> 3;
  const u16* Bt = Wt3 + (size_t)seg * 1024 * 1024;
  u16* C = Out3 + (size_t)seg * 4096 * 1024;
  const float* bias = (seg == 0) ? bq : (seg == 2) ? bv : nullptr;
  const float scale = (seg == 2) ? 1.0f : QKSCALE_E2;   // exp2-domain fold

  const int tid = threadIdx.x;
  const int lane = tid & 63;
  const int w = tid >> 6;
  const int m0 = bx * 128;
  const int n0 = by * 128;
  __shared__ u16 As[2][64 * 64];   // 8KB per buf (128 logical rows x 32 cols, row-paired)
  __shared__ u16 Bs[2][64 * 64];
  floatx4 acc[4][4];
#pragma unroll
  for (int i = 0; i < 4; ++i)
#pragma unroll
    for (int j = 0; j < 4; ++j) acc[i][j] = (floatx4){0.f, 0.f, 0.f, 0.f};
  const int wr = (w >> 1) * 64;
  const int wc = (w & 1) * 64;
  const int g = lane >> 4;
  const int lr = lane & 15;

  auto stage = [&](int k0, int buf) {
#pragma unroll
    for (int p = 0; p < 2; ++p) {
      int L = tid * 16 + p * 4096;
      int lrow = L >> 7;                      // 0..63 LDS row (128B)
      int un = (L & 127) ^ ((lrow & 7) << 4); // un-swizzled intra-row byte
      int r = lrow * 2 + (un >> 6);           // logical row 0..127
      int cb = un & 63;                       // k-byte 0..63 (32 elems)
      gload_lds16((const char*)A + (size_t)(m0 + r) * 2048 + k0 * 2 + cb,
                  (char*)As[buf] + p * 4096 + w * 1024);
      gload_lds16((const char*)Bt + (size_t)(n0 + r) * 2048 + k0 * 2 + cb,
                  (char*)Bs[buf] + p * 4096 + w * 1024);
    }
  };

  stage(0, 0);
  for (int t = 0; t < 32; ++t) {             // 32 K-steps of 32
    const int buf = t & 1;
    __syncthreads();                         // drains stage(t); guards buf reuse
    if (t + 1 < 32) stage((t + 1) << 5, buf ^ 1);
    const u16* as = As[buf];
    const u16* bs = Bs[buf];
    short8 af[4], bf[4];
#pragma unroll
    for (int mi = 0; mi < 4; ++mi) {
      int r = wr + mi * 16 + lr;
      af[mi] = *(const short8*)((const char*)as +
               ((r >> 1) * 128 + ((((r & 1) << 6) | (g * 16)) ^ (((r >> 1) & 7) << 4))));
    }
#pragma unroll
    for (int ni = 0; ni < 4; ++ni) {
      int r = wc + ni * 16 + lr;
      bf[ni] = *(const short8*)((const char*)bs +
               ((r >> 1) * 128 + ((((r & 1) << 6) | (g * 16)) ^ (((r >> 1) & 7) << 4))));
    }
    __builtin_amdgcn_s_setprio(1);
#pragma unroll
    for (int mi = 0; mi < 4; ++mi)
#pragma unroll
      for (int ni = 0; ni < 4; ++ni)
        acc[mi][ni] = __builtin_amdgcn_mfma_f32_16x16x32_bf16(af[mi], bf[ni],
                                                              acc[mi][ni], 0, 0, 0);
    __builtin_amdgcn_s_setprio(0);
  }

  if (seg == 2) {
    // ---- direct V^T epilogue: vtb[bseg*1024 + d][s], 8B stores (4 s-consecutive) ----
    const int bseg = m0 >> 11;                 // batch of this block (tile never straddles)
    const int s0 = (m0 & 2047) + wr + g * 4;   // s base for this lane's rows
#pragma unroll
    for (int ni = 0; ni < 4; ++ni) {
      int d = n0 + wc + ni * 16 + lr;
      float bvv = bv[d];
      u16* vrow = Vt + (size_t)(bseg * 1024 + d) * 2048;
#pragma unroll
      for (int mi = 0; mi < 4; ++mi) {
        ushort4v pk = { f2b(acc[mi][ni][0] + bvv), f2b(acc[mi][ni][1] + bvv),
                        f2b(acc[mi][ni][2] + bvv), f2b(acc[mi][ni][3] + bvv) };
        *(ushort4v*)(vrow + s0 + mi * 16) = pk;
      }
    }
    return;                                    // block-uniform: no barrier divergence
  }

  // ---- coalesced epilogue via per-wave LDS bounce (seg 0/1) ----
  __syncthreads();                            // all K-loop LDS reads done
  u16* eb = (w == 0) ? (u16*)As[0] : (w == 1) ? (u16*)As[1]
          : (w == 2) ? (u16*)Bs[0] : (u16*)Bs[1];   // 8KB per wave; use [16][72]
  const int rr = lane >> 2;                   // 0..15 (row within 16-row strip)
  const int cc = lane & 3;                    // 0..3  (16-col chunk)
  float bv4[4];
#pragma unroll
  for (int ni = 0; ni < 4; ++ni)
    bv4[ni] = bias ? bias[n0 + wc + ni * 16 + lr] : 0.f;
#pragma unroll
  for (int mi = 0; mi < 4; ++mi) {
#pragma unroll
    for (int ni = 0; ni < 4; ++ni)
#pragma unroll
      for (int r = 0; r < 4; ++r)
        eb[(g * 4 + r) * 72 + ni * 16 + lr] =
            f2b((acc[mi][ni][r] + bv4[ni]) * scale);
    short8 v0 = *(const short8*)(eb + rr * 72 + cc * 16);
    short8 v1 = *(const short8*)(eb + rr * 72 + cc * 16 + 8);
    u16* dst = C + (size_t)(m0 + wr + mi * 16 + rr) * 1024 + n0 + wc + cc * 16;
    *(short8*)dst = v0;
    *(short8*)(dst + 8) = v1;
  }
}

// ------------- flash attention: DUAL q-stream, shared K/V frag reads -------------
// 512 blocks x 4 waves; block covers q-tile pair (p, 31-p): UNIFORM 33 tiles/block
// (zero tail, no dispatch assumptions). Each wave owns 16 rows of BOTH streams and
// reads each kf/vf fragment ONCE for both -> LDS read traffic per q-row cut ~40%
// (the round-17 diagnosis: flash is LDS-read-throughput-bound, K/V reads were 4x
// redundant across waves AND unshared across rows). LDS 48KB.
__device__ __forceinline__ void stream_softmax(floatx4 (&sa)[4], float& m, float& l,
                                               floatx4 (&acc)[4], u16* pl,
                                               bool diag, int wlr, int g, int lr) {
  if (diag) {
#pragma unroll
    for (int ct = 0; ct < 4; ++ct)
#pragma unroll
      for (int r = 0; r < 4; ++r)
        if (ct * 16 + g * 4 + r > wlr) sa[ct][r] += NEGBIG;
  }
  floatx4 v = vmax4(vmax4(sa[0], sa[1]), vmax4(sa[2], sa[3]));
  float mx = fmaxf(fmaxf(v[0], v[1]), fmaxf(v[2], v[3]));
  mx = fmaxf(mx, __shfl_xor(mx, 16, 64));
  mx = fmaxf(mx, __shfl_xor(mx, 32, 64));
  if (!__all(mx <= m + 8.f)) {
    float mn = fmaxf(m, mx);
    float al = ex2(m - mn);
    l *= al;
#pragma unroll
    for (int dt = 0; dt < 4; ++dt) acc[dt] *= al;
    m = mn;
  }
  floatx4 p[4];
#pragma unroll
  for (int ct = 0; ct < 4; ++ct)
#pragma unroll
    for (int r = 0; r < 4; ++r)
      p[ct][r] = ex2(sa[ct][r] - m);
  floatx4 s = (p[0] + p[1]) + (p[2] + p[3]);
  float rs = (s[0] + s[1]) + (s[2] + s[3]);
  rs += __shfl_xor(rs, 16, 64);
  rs += __shfl_xor(rs, 32, 64);
  l += rs;
#pragma unroll
  for (int ct = 0; ct < 4; ++ct) {
    ushort4v pk = { bconv(p[ct][0]), bconv(p[ct][1]),
                    bconv(p[ct][2]), bconv(p[ct][3]) };
    *(ushort4v*)((char*)pl + ((lr * 128 + ct * 32 + g * 8) ^ ((lr & 7) << 4))) = pk;
  }
}

__global__ __launch_bounds__(256, 3)
void flash_attn(const u16* __restrict__ q, const u16* __restrict__ k,
                const u16* __restrict__ vt, u16* __restrict__ o) {
  const int tid = threadIdx.x;
  const int lane = tid & 63;
  const int w = tid >> 6;
  const int g = lane >> 4;
  const int lr = lane & 15;
  // 512 blocks: x=id&7 (XCD stream, 4 heads each), s=head-in-XCD, p=pair index
  const int id = (int)blockIdx.x;
  const int x = id & 7;
  const int rest = id >> 3;           // 0..63
  const int s = rest & 3;
  const int p = rest >> 2;            // 0..15
  const int head = x * 4 + s;
  const int b = head >> 4;
  const int h = head & 15;
  const int qtA = p, qtB = 31 - p;
  const int rowA = qtA * 64 + w * 16;
  const int rowB = qtB * 64 + w * 16;
  const int wlr = w * 16 + lr;

  __shared__ u16 Ks[2][64 * 64];      // 16KB
  __shared__ u16 Vs[2][64 * 64];      // 16KB
  __shared__ u16 Pl[4][2][16 * 64];   // 16KB: [wave][stream]

  short8 qfA[2], qfB[2];
  {
    const u16* qa = q + (size_t)(b * SS + rowA + lr) * DD + h * HD + g * 8;
    qfA[0] = *(const short8*)qa;
    qfA[1] = *(const short8*)(qa + 32);
    const u16* qb = q + (size_t)(b * SS + rowB + lr) * DD + h * HD + g * 8;
    qfB[0] = *(const short8*)qb;
    qfB[1] = *(const short8*)(qb + 32);
  }
  floatx4 accA[4], accB[4];
#pragma unroll
  for (int dt = 0; dt < 4; ++dt) {
    accA[dt] = (floatx4){0.f, 0.f, 0.f, 0.f};
    accB[dt] = (floatx4){0.f, 0.f, 0.f, 0.f};
  }
  float mA = -1e30f, lA = 0.f, mB = -1e30f, lB = 0.f;

  const char* kbase = (const char*)(k + (size_t)(b * SS) * DD + h * HD);
  const char* vbase = (const char*)(vt + (size_t)((b * HH + h) * HD) * SS);
  const int nt = qtB + 1;

  auto stage = [&](int t, int buf) {
    const int kvb = t * 64;
#pragma unroll
    for (int pp = 0; pp < 2; ++pp) {
      int L = tid * 16 + pp * 4096;
      int row = L >> 7;
      int cb = (L ^ ((row & 7) << 4)) & 127;
      gload_lds16(kbase + (size_t)(kvb + row) * (DD * 2) + cb,
                  (char*)Ks + buf * 8192 + pp * 4096 + w * 1024);
      gload_lds16(vbase + (size_t)row * (SS * 2) + kvb * 2 + cb,
                  (char*)Vs + buf * 8192 + pp * 4096 + w * 1024);
    }
  };

  stage(0, 0);
  int cur = 0;
  for (int t = 0; t < nt; ++t) {
    __syncthreads();
    if (t + 1 < nt) stage(t + 1, cur ^ 1);
    const u16* kc = Ks[cur];
    const u16* vc = Vs[cur];
    const bool actA = (t <= qtA);

    floatx4 saA[4], saB[4];
#pragma unroll
    for (int ct = 0; ct < 4; ++ct) {
      saA[ct] = (floatx4){0.f, 0.f, 0.f, 0.f};
      saB[ct] = (floatx4){0.f, 0.f, 0.f, 0.f};
    }
    __builtin_amdgcn_s_setprio(1);
#pragma unroll
    for (int ks = 0; ks < 2; ++ks) {
      const int c0 = ks * 32 + g * 8;
#pragma unroll
      for (int ct = 0; ct < 4; ++ct) {
        int row = ct * 16 + lr;
        short8 kf = *(const short8*)(kc + row * 64 + (c0 ^ ((row & 7) << 3)));
        saB[ct] = __builtin_amdgcn_mfma_f32_16x16x32_bf16(kf, qfB[ks], saB[ct], 0, 0, 0);
        if (actA)
          saA[ct] = __builtin_amdgcn_mfma_f32_16x16x32_bf16(kf, qfA[ks], saA[ct], 0, 0, 0);
      }
    }
    __builtin_amdgcn_s_setprio(0);

    if (actA)
      stream_softmax(saA, mA, lA, accA, Pl[w][0], t == qtA, wlr, g, lr);
    stream_softmax(saB, mB, lB, accB, Pl[w][1], t == qtB, wlr, g, lr);

    __builtin_amdgcn_s_setprio(1);
#pragma unroll
    for (int ks = 0; ks < 2; ++ks) {
      const int c0 = ks * 32 + g * 8;
      int pby = (lr * 128 + ks * 64 + g * 16) ^ ((lr & 7) << 4);
      short8 pfB = *(const short8*)((const char*)Pl[w][1] + pby);
      short8 pfA = pfB;
      if (actA) pfA = *(const short8*)((const char*)Pl[w][0] + pby);
#pragma unroll
      for (int dt = 0; dt < 4; ++dt) {
        int row = dt * 16 + lr;
        short8 vf = *(const short8*)(vc + row * 64 + (c0 ^ ((row & 7) << 3)));
        accB[dt] = __builtin_amdgcn_mfma_f32_16x16x32_bf16(vf, pfB, accB[dt], 0, 0, 0);
        if (actA)
          accA[dt] = __builtin_amdgcn_mfma_f32_16x16x32_bf16(vf, pfA, accA[dt], 0, 0, 0);
      }
    }
    __builtin_amdgcn_s_setprio(0);
    cur ^= 1;
  }

  float invA = 1.0f / lA;
  float invB = 1.0f / lB;
#pragma unroll
  for (int dt = 0; dt < 4; ++dt) {
    ushort4v pa = { bconv(accA[dt][0] * invA), bconv(accA[dt][1] * invA),
                    bconv(accA[dt][2] * invA), bconv(accA[dt][3] * invA) };
    ushort4v pb = { bconv(accB[dt][0] * invB), bconv(accB[dt][1] * invB),
                    bconv(accB[dt][2] * invB), bconv(accB[dt][3] * invB) };
    *(ushort4v*)(o + (size_t)(b * SS + rowA + lr) * DD + h * HD + dt * 16 + g * 4) = pa;
    *(ushort4v*)(o + (size_t)(b * SS + rowB + lr) * DD + h * HD + dt * 16 + g * 4) = pb;
  }
}

extern "C" void kernel_launch(void* const* d_in, const int* in_sizes, int n_in,
                              void* d_out, int out_size, void* d_ws, size_t ws_size,
                              hipStream_t stream) {
  const float* x  = (const float*)d_in[0];
  // d_in[1] = mask: causal additive -1e9, replicated analytically in-kernel
  const float* Wq = (const float*)d_in[2];
  const float* bq = (const float*)d_in[3];
  const float* Wk = (const float*)d_in[4];
  const float* Wv = (const float*)d_in[5];
  const float* bv = (const float*)d_in[6];
  const float* Wo = (const float*)d_in[7];
  const float* bo = (const float*)d_in[8];
  float* out = (float*)d_out;

  char* ws = (char*)d_ws;
  u16* xb  = (u16*)(ws);                    // 8MB  x bf16 [4096][1024]
  u16* wt  = (u16*)(ws + (8u << 20));       // 8MB  Wq^T,Wk^T,Wv^T,Wo^T bf16
  u16* qkv = (u16*)(ws + (16u << 20));      // 24MB q,k bf16 [4096][1024] (v slab unused)
  u16* vtb = (u16*)(ws + (40u << 20));      // 8MB  v^T per batch [B*D][S] (written by qkv)
  u16* ob  = (u16*)(ws + (48u << 20));      // 8MB  attn out bf16
  u16* wot = wt + 3u * 1024 * 1024;

  dim3 tb(32, 8);
  cvt_bf16x4<<<4096, 256, 0, stream>>>((const float4*)x, (ushort4v*)xb,
                                       (BB * SS * DD) / 4);
  transpose_w<<<dim3(32, 32, 4), tb, 0, stream>>>(Wq, Wk, Wv, Wo, wt);
  gemm_qkv<<<768, 256, 0, stream>>>(xb, wt, qkv, vtb, bq, bv);
  flash_attn<<<512, 256, 0, stream>>>(qkv, qkv + (size_t)4096 * 1024, vtb, ob);
  gemm_bt<float><<<512, 256, 0, stream>>>(ob, wot, out, bo, 1.0f,
                                          4096, 1024, 1024);
}

// Round 19
// 114.147 us; speedup vs baseline: 1.0800x; 1.0800x over previous
//
#include <hip/hip_runtime.h>
#include <hip/hip_bf16.h>

// Problem constants (Whisper-style MHA): B=2, S=2048, D=1024, H=16, hd=64
#define BB 2
#define SS 2048
#define DD 1024
#define HH 16
#define HD 64
#define QKSCALE 0.35355339059327373f   // 64^-0.25
// 64^-0.25 * sqrt(log2(e)) : folds exp->exp2 domain change into q,k projections
#define QKSCALE_E2 0.42466090144f
#define NEGBIG (-1e9f)

using u16 = unsigned short;
typedef __attribute__((ext_vector_type(8))) short short8;     // 8 bf16 = 4 VGPR
typedef __attribute__((ext_vector_type(4))) float floatx4;    // MFMA acc
typedef __attribute__((ext_vector_type(4))) unsigned short ushort4v;

#define GLOBAL_AS __attribute__((address_space(1)))
#define LDS_AS __attribute__((address_space(3)))

__device__ __forceinline__ u16 f2b(float f) {          // RNE f32->bf16
  union { float f; unsigned u; } v; v.f = f;
  return (u16)((v.u + 0x7fffu + ((v.u >> 16) & 1u)) >> 16);
}

__device__ __forceinline__ u16 bconv(float f) {        // via HW cvt (fuses to cvt_pk)
  union { __hip_bfloat16 h; u16 u; } cv;
  cv.h = __float2bfloat16(f);
  return cv.u;
}

__device__ __forceinline__ float ex2(float f) {        // raw v_exp_f32 (2^x)
  return __builtin_amdgcn_exp2f(f);
}

__device__ __forceinline__ floatx4 vmax4(floatx4 a, floatx4 b) {
  return (floatx4){fmaxf(a[0], b[0]), fmaxf(a[1], b[1]),
                   fmaxf(a[2], b[2]), fmaxf(a[3], b[3])};
}

__device__ __forceinline__ void gload_lds16(const void* g, void* l) {
  __builtin_amdgcn_global_load_lds((GLOBAL_AS void*)(g), (LDS_AS void*)(l), 16, 0, 0);
}

// ---------------- elementwise f32 -> bf16 ----------------
__global__ __launch_bounds__(256) void cvt_bf16x4(const float4* __restrict__ src,
                                                  ushort4v* __restrict__ dst, int n4) {
  int i = blockIdx.x * 256 + threadIdx.x;
  if (i >= n4) return;
  float4 f = src[i];
  ushort4v o = { f2b(f.x), f2b(f.y), f2b(f.z), f2b(f.w) };
  dst[i] = o;
}

// ------------- weight transpose+convert: W[K][N] f32 -> Wt[N][K] bf16 (4 weights) -------------
__global__ __launch_bounds__(256) void transpose_w(const float* __restrict__ s0,
                                                   const float* __restrict__ s1,
                                                   const float* __restrict__ s2,
                                                   const float* __restrict__ s3,
                                                   u16* __restrict__ dst) {
  __shared__ float tile[32][33];
  const float* src = (blockIdx.z == 0) ? s0 : (blockIdx.z == 1) ? s1
                   : (blockIdx.z == 2) ? s2 : s3;
  u16* d = dst + (size_t)blockIdx.z * 1024 * 1024;
  int c0 = blockIdx.x * 32, r0 = blockIdx.y * 32;
  int tx = threadIdx.x, ty = threadIdx.y;     // block (32,8)
#pragma unroll
  for (int i = 0; i < 4; ++i)
    tile[ty + i * 8][tx] = src[(size_t)(r0 + ty + i * 8) * 1024 + c0 + tx];
  __syncthreads();
#pragma unroll
  for (int i = 0; i < 4; ++i)
    d[(size_t)(c0 + ty + i * 8) * 1024 + r0 + tx] = f2b(tile[tx][ty + i * 8]);
}

// ------------- out-proj GEMM: 64x128 tile, BK=64, dbuf prefetch, XCD swizzle -------------
template <typename OutT>
__global__ __launch_bounds__(256, 3)
void gemm_bt(const u16* __restrict__ A, const u16* __restrict__ Bt,
             OutT* __restrict__ C, const float* __restrict__ bias,
             float scale, int M, int N, int K) {
  const int tid = threadIdx.x;
  const int lane = tid & 63;
  const int w = tid >> 6;
  const int id = (int)blockIdx.x;
  const int swz = (id & 7) * 64 + (id >> 3);
  const int m0 = (swz & 63) * 64;
  const int n0 = (swz >> 6) * 128;
  __shared__ u16 As[2][64 * 64];     // 8KB per buf
  __shared__ u16 Bs[2][128 * 64];    // 16KB per buf
  floatx4 acc[2][4];
#pragma unroll
  for (int i = 0; i < 2; ++i)
#pragma unroll
    for (int j = 0; j < 4; ++j) acc[i][j] = (floatx4){0.f, 0.f, 0.f, 0.f};

  const int wr = (w >> 1) * 32;
  const int wc = (w & 1) * 64;
  const int g = lane >> 4;
  const int lr = lane & 15;
  const size_t strideA = (size_t)K * 2;

  auto stage = [&](int k0, int buf) {
#pragma unroll
    for (int p = 0; p < 2; ++p) {    // A: 8KB
      int L = tid * 16 + p * 4096;
      int row = L >> 7;
      int cb = (L ^ ((row & 7) << 4)) & 127;
      gload_lds16((const char*)A + (size_t)(m0 + row) * strideA + k0 * 2 + cb,
                  (char*)As[buf] + p * 4096 + w * 1024);
    }
#pragma unroll
    for (int p = 0; p < 4; ++p) {    // B: 16KB
      int L = tid * 16 + p * 4096;
      int row = L >> 7;
      int cb = (L ^ ((row & 7) << 4)) & 127;
      gload_lds16((const char*)Bt + (size_t)(n0 + row) * strideA + k0 * 2 + cb,
                  (char*)Bs[buf] + p * 4096 + w * 1024);
    }
  };

  const int nsteps = K >> 6;
  stage(0, 0);
  for (int t = 0; t < nsteps; ++t) {
    const int buf = t & 1;
    __syncthreads();                       // drains stage(t); guards buf reuse
    if (t + 1 < nsteps) stage((t + 1) << 6, buf ^ 1);
    const u16* as = As[buf];
    const u16* bs = Bs[buf];
#pragma unroll
    for (int ks = 0; ks < 2; ++ks) {
      short8 af[2], bf[4];
      const int c0 = ks * 32 + g * 8;
#pragma unroll
      for (int mi = 0; mi < 2; ++mi) {
        int row = wr + mi * 16 + lr;
        af[mi] = *(const short8*)(as + row * 64 + (c0 ^ ((row & 7) << 3)));
      }
#pragma unroll
      for (int ni = 0; ni < 4; ++ni) {
        int row = wc + ni * 16 + lr;
        bf[ni] = *(const short8*)(bs + row * 64 + (c0 ^ ((row & 7) << 3)));
      }
      __builtin_amdgcn_s_setprio(1);
#pragma unroll
      for (int mi = 0; mi < 2; ++mi)
#pragma unroll
        for (int ni = 0; ni < 4; ++ni)
          acc[mi][ni] = __builtin_amdgcn_mfma_f32_16x16x32_bf16(af[mi], bf[ni],
                                                                acc[mi][ni], 0, 0, 0);
      __builtin_amdgcn_s_setprio(0);
    }
  }
#pragma unroll
  for (int ni = 0; ni < 4; ++ni) {
    int col = n0 + wc + ni * 16 + lr;
    float bvv = bias ? bias[col] : 0.f;
#pragma unroll
    for (int mi = 0; mi < 2; ++mi) {
#pragma unroll
      for (int r = 0; r < 4; ++r) {
        int rowg = m0 + wr + mi * 16 + g * 4 + r;
        float val = (acc[mi][ni][r] + bvv) * scale;
        if constexpr (sizeof(OutT) == 4) C[(size_t)rowg * N + col] = val;
        else C[(size_t)rowg * N + col] = (OutT)f2b(val);
      }
    }
  }
}

// ------------- fused QKV GEMM: 64x128 tile, BK=64 dbuf (gemm_bt's measured-best structure) ---
// grid 1536 (64 m x 8 n x 3 seg), 3 blocks/CU -> uniform 2 residency rounds; XCD swizzle
// gives each XCD 192 consecutive logical blocks (3 L2-resident B panels).
// Epilogues: seg 0/1 -> per-wave LDS-bounce coalesced bf16 stores; seg 2 -> direct V^T.
__global__ __launch_bounds__(256, 3)
void gemm_qkv(const u16* __restrict__ A, const u16* __restrict__ Wt3,
              u16* __restrict__ Out3, u16* __restrict__ Vt,
              const float* __restrict__ bq, const float* __restrict__ bv) {
  const int tid = threadIdx.x;
  const int lane = tid & 63;
  const int w = tid >> 6;
  const int id = (int)blockIdx.x;
  const int swz = (id & 7) * 192 + (id >> 3);   // bijective, 1536 % 8 == 0
  const int seg = swz >> 9;                     // 512 blocks per segment
  const int r2 = swz & 511;
  const int m0 = (r2 & 63) * 64;
  const int n0 = (r2 >> 6) * 128;
  const u16* Bt = Wt3 + (size_t)seg * 1024 * 1024;
  u16* C = Out3 + (size_t)seg * 4096 * 1024;

  __shared__ u16 As[2][64 * 64];     // 8KB per buf
  __shared__ u16 Bs[2][128 * 64];    // 16KB per buf
  floatx4 acc[2][4];
#pragma unroll
  for (int i = 0; i < 2; ++i)
#pragma unroll
    for (int j = 0; j < 4; ++j) acc[i][j] = (floatx4){0.f, 0.f, 0.f, 0.f};

  const int wr = (w >> 1) * 32;
  const int wc = (w & 1) * 64;
  const int g = lane >> 4;
  const int lr = lane & 15;

  auto stage = [&](int k0, int buf) {
#pragma unroll
    for (int p = 0; p < 2; ++p) {    // A: 8KB
      int L = tid * 16 + p * 4096;
      int row = L >> 7;
      int cb = (L ^ ((row & 7) << 4)) & 127;
      gload_lds16((const char*)A + (size_t)(m0 + row) * 2048 + k0 * 2 + cb,
                  (char*)As[buf] + p * 4096 + w * 1024);
    }
#pragma unroll
    for (int p = 0; p < 4; ++p) {    // B: 16KB
      int L = tid * 16 + p * 4096;
      int row = L >> 7;
      int cb = (L ^ ((row & 7) << 4)) & 127;
      gload_lds16((const char*)Bt + (size_t)(n0 + row) * 2048 + k0 * 2 + cb,
                  (char*)Bs[buf] + p * 4096 + w * 1024);
    }
  };

  stage(0, 0);
  for (int t = 0; t < 16; ++t) {
    const int buf = t & 1;
    __syncthreads();                       // drains stage(t); guards buf reuse
    if (t + 1 < 16) stage((t + 1) << 6, buf ^ 1);
    const u16* as = As[buf];
    const u16* bs = Bs[buf];
#pragma unroll
    for (int ks = 0; ks < 2; ++ks) {
      short8 af[2], bf[4];
      const int c0 = ks * 32 + g * 8;
#pragma unroll
      for (int mi = 0; mi < 2; ++mi) {
        int row = wr + mi * 16 + lr;
        af[mi] = *(const short8*)(as + row * 64 + (c0 ^ ((row & 7) << 3)));
      }
#pragma unroll
      for (int ni = 0; ni < 4; ++ni) {
        int row = wc + ni * 16 + lr;
        bf[ni] = *(const short8*)(bs + row * 64 + (c0 ^ ((row & 7) << 3)));
      }
      __builtin_amdgcn_s_setprio(1);
#pragma unroll
      for (int mi = 0; mi < 2; ++mi)
#pragma unroll
        for (int ni = 0; ni < 4; ++ni)
          acc[mi][ni] = __builtin_amdgcn_mfma_f32_16x16x32_bf16(af[mi], bf[ni],
                                                                acc[mi][ni], 0, 0, 0);
      __builtin_amdgcn_s_setprio(0);
    }
  }

  if (seg == 2) {
    // ---- direct V^T epilogue: vtb[bseg*1024 + d][s], 8B stores (4 s-consecutive) ----
    const int bseg = m0 >> 11;                 // 64-row tile never straddles batches
    const int s0 = (m0 & 2047) + wr + g * 4;
#pragma unroll
    for (int ni = 0; ni < 4; ++ni) {
      int d = n0 + wc + ni * 16 + lr;
      float bvv = bv[d];
      u16* vrow = Vt + (size_t)(bseg * 1024 + d) * 2048;
#pragma unroll
      for (int mi = 0; mi < 2; ++mi) {
        ushort4v pk = { f2b(acc[mi][ni][0] + bvv), f2b(acc[mi][ni][1] + bvv),
                        f2b(acc[mi][ni][2] + bvv), f2b(acc[mi][ni][3] + bvv) };
        *(ushort4v*)(vrow + s0 + mi * 16) = pk;
      }
    }
    return;                                    // block-uniform: no barrier divergence
  }

  // ---- coalesced epilogue via per-wave LDS bounce (seg 0/1) ----
  __syncthreads();                             // all K-loop LDS reads complete
  u16* eb = (u16*)As + w * 1152;               // per-wave [16][72] u16 scratch (2304B)
  const float scale = QKSCALE_E2;
  float bv4[4];
#pragma unroll
  for (int ni = 0; ni < 4; ++ni)
    bv4[ni] = (seg == 0) ? bq[n0 + wc + ni * 16 + lr] : 0.f;
#pragma unroll
  for (int mi = 0; mi < 2; ++mi) {
#pragma unroll
    for (int ni = 0; ni < 4; ++ni)
#pragma unroll
      for (int r = 0; r < 4; ++r)
        eb[(g * 4 + r) * 72 + ni * 16 + lr] =
            f2b((acc[mi][ni][r] + bv4[ni]) * scale);
#pragma unroll
    for (int jj = 0; jj < 2; ++jj) {
      int row = (lane >> 3) + jj * 8;          // 0..15
      int ch = lane & 7;                       // 8-chunk of 8 u16 (16B)
      short8 vv = *(const short8*)(eb + row * 72 + ch * 8);
      *(short8*)(C + (size_t)(m0 + wr + mi * 16 + row) * 1024 + n0 + wc + ch * 8) = vv;
    }
  }
}

// ------------- flash attention: swapped-QK (S^T), single stream, 1 q-tile/block -------------
// (settled round-10 structure: P via LDS, 40KB, 4 blocks/CU, balanced qt mapping —
// survived 8 structural challenges; frozen)
__device__ __forceinline__ void stream_softmax(floatx4 (&sa)[4], float& m, float& l,
                                               floatx4 (&acc)[4], u16* pl,
                                               bool diag, int wlr, int g, int lr) {
  if (diag) {
#pragma unroll
    for (int ct = 0; ct < 4; ++ct)
#pragma unroll
      for (int r = 0; r < 4; ++r)
        if (ct * 16 + g * 4 + r > wlr) sa[ct][r] += NEGBIG;
  }
  floatx4 v = vmax4(vmax4(sa[0], sa[1]), vmax4(sa[2], sa[3]));
  float mx = fmaxf(fmaxf(v[0], v[1]), fmaxf(v[2], v[3]));
  mx = fmaxf(mx, __shfl_xor(mx, 16, 64));
  mx = fmaxf(mx, __shfl_xor(mx, 32, 64));
  if (!__all(mx <= m + 8.f)) {
    float mn = fmaxf(m, mx);
    float al = ex2(m - mn);
    l *= al;
#pragma unroll
    for (int dt = 0; dt < 4; ++dt) acc[dt] *= al;
    m = mn;
  }
  floatx4 p[4];
#pragma unroll
  for (int ct = 0; ct < 4; ++ct)
#pragma unroll
    for (int r = 0; r < 4; ++r)
      p[ct][r] = ex2(sa[ct][r] - m);
  floatx4 s = (p[0] + p[1]) + (p[2] + p[3]);
  float rs = (s[0] + s[1]) + (s[2] + s[3]);
  rs += __shfl_xor(rs, 16, 64);
  rs += __shfl_xor(rs, 32, 64);
  l += rs;
#pragma unroll
  for (int ct = 0; ct < 4; ++ct) {
    ushort4v pk = { bconv(p[ct][0]), bconv(p[ct][1]),
                    bconv(p[ct][2]), bconv(p[ct][3]) };
    *(ushort4v*)((char*)pl + ((lr * 128 + ct * 32 + g * 8) ^ ((lr & 7) << 4))) = pk;
  }
}

__global__ __launch_bounds__(256, 4)
void flash_attn(const u16* __restrict__ q, const u16* __restrict__ k,
                const u16* __restrict__ vt, u16* __restrict__ o) {
  const int tid = threadIdx.x;
  const int lane = tid & 63;
  const int w = tid >> 6;
  const int g = lane >> 4;
  const int lr = lane & 15;
  const int i = (int)blockIdx.x;      // 0..1023
  const int x = i & 7;
  const int kk = i >> 3;              // 0..127
  const int s = kk & 3;
  const int mI = kk >> 2;             // 0..31
  const int u = mI >> 3;
  const int v = mI & 7;
  const int gg = x * 4 + s;           // (b,h), 4 groups per XCD stream
  const int b = gg >> 4;
  const int h = gg & 15;
  const int a = (u + s) & 3;
  const int qt = (a == 0) ? v : (a == 1) ? (31 - v) : (a == 2) ? (16 + v) : (15 - v);
  const int row0 = qt * 64 + w * 16;
  const int wlr = w * 16 + lr;

  __shared__ u16 Ks[2][64 * 64];      // 16KB
  __shared__ u16 Vs[2][64 * 64];      // 16KB
  __shared__ u16 Pl[4][16 * 64];      // 8KB

  short8 qf[2];
  {
    const u16* qp = q + (size_t)(b * SS + row0 + lr) * DD + h * HD + g * 8;
    qf[0] = *(const short8*)qp;
    qf[1] = *(const short8*)(qp + 32);
  }
  floatx4 acc[4];
#pragma unroll
  for (int dt = 0; dt < 4; ++dt) acc[dt] = (floatx4){0.f, 0.f, 0.f, 0.f};
  float m = -1e30f, l = 0.f;

  const char* kbase = (const char*)(k + (size_t)(b * SS) * DD + h * HD);
  const char* vbase = (const char*)(vt + (size_t)((b * HH + h) * HD) * SS);
  const int nt = qt + 1;

  auto stage = [&](int t, int buf) {
    const int kvb = t * 64;
#pragma unroll
    for (int p = 0; p < 2; ++p) {
      int L = tid * 16 + p * 4096;
      int row = L >> 7;
      int cb = (L ^ ((row & 7) << 4)) & 127;
      gload_lds16(kbase + (size_t)(kvb + row) * (DD * 2) + cb,
                  (char*)Ks + buf * 8192 + p * 4096 + w * 1024);
      gload_lds16(vbase + (size_t)row * (SS * 2) + kvb * 2 + cb,
                  (char*)Vs + buf * 8192 + p * 4096 + w * 1024);
    }
  };

  stage(0, 0);
  int cur = 0;
  for (int t = 0; t < nt; ++t) {
    __syncthreads();
    if (t + 1 < nt) stage(t + 1, cur ^ 1);
    const u16* kc = Ks[cur];
    const u16* vc = Vs[cur];

    floatx4 sa[4];
#pragma unroll
    for (int ct = 0; ct < 4; ++ct) sa[ct] = (floatx4){0.f, 0.f, 0.f, 0.f};
    __builtin_amdgcn_s_setprio(1);
#pragma unroll
    for (int ks = 0; ks < 2; ++ks) {
      const int c0 = ks * 32 + g * 8;
#pragma unroll
      for (int ct = 0; ct < 4; ++ct) {
        int row = ct * 16 + lr;
        short8 kf = *(const short8*)(kc + row * 64 + (c0 ^ ((row & 7) << 3)));
        sa[ct] = __builtin_amdgcn_mfma_f32_16x16x32_bf16(kf, qf[ks], sa[ct], 0, 0, 0);
      }
    }
    __builtin_amdgcn_s_setprio(0);

    stream_softmax(sa, m, l, acc, Pl[w], t == qt, wlr, g, lr);

    __builtin_amdgcn_s_setprio(1);
#pragma unroll
    for (int ks = 0; ks < 2; ++ks) {
      const int c0 = ks * 32 + g * 8;
      int pby = (lr * 128 + ks * 64 + g * 16) ^ ((lr & 7) << 4);
      short8 pf = *(const short8*)((const char*)Pl[w] + pby);
#pragma unroll
      for (int dt = 0; dt < 4; ++dt) {
        int row = dt * 16 + lr;
        short8 vf = *(const short8*)(vc + row * 64 + (c0 ^ ((row & 7) << 3)));
        acc[dt] = __builtin_amdgcn_mfma_f32_16x16x32_bf16(vf, pf, acc[dt], 0, 0, 0);
      }
    }
    __builtin_amdgcn_s_setprio(0);
    cur ^= 1;
  }

  float inv = 1.0f / l;
#pragma unroll
  for (int dt = 0; dt < 4; ++dt) {
    ushort4v pa = { bconv(acc[dt][0] * inv), bconv(acc[dt][1] * inv),
                    bconv(acc[dt][2] * inv), bconv(acc[dt][3] * inv) };
    *(ushort4v*)(o + (size_t)(b * SS + row0 + lr) * DD + h * HD + dt * 16 + g * 4) = pa;
  }
}

extern "C" void kernel_launch(void* const* d_in, const int* in_sizes, int n_in,
                              void* d_out, int out_size, void* d_ws, size_t ws_size,
                              hipStream_t stream) {
  const float* x  = (const float*)d_in[0];
  // d_in[1] = mask: causal additive -1e9, replicated analytically in-kernel
  const float* Wq = (const float*)d_in[2];
  const float* bq = (const float*)d_in[3];
  const float* Wk = (const float*)d_in[4];
  const float* Wv = (const float*)d_in[5];
  const float* bv = (const float*)d_in[6];
  const float* Wo = (const float*)d_in[7];
  const float* bo = (const float*)d_in[8];
  float* out = (float*)d_out;

  char* ws = (char*)d_ws;
  u16* xb  = (u16*)(ws);                    // 8MB  x bf16 [4096][1024]
  u16* wt  = (u16*)(ws + (8u << 20));       // 8MB  Wq^T,Wk^T,Wv^T,Wo^T bf16
  u16* qkv = (u16*)(ws + (16u << 20));      // q,k bf16 [4096][1024] (v slab unused)
  u16* vtb = (u16*)(ws + (40u << 20));      // 8MB  v^T per batch [B*D][S] (written by qkv)
  u16* ob  = (u16*)(ws + (48u << 20));      // 8MB  attn out bf16
  u16* wot = wt + 3u * 1024 * 1024;

  dim3 tb(32, 8);
  cvt_bf16x4<<<4096, 256, 0, stream>>>((const float4*)x, (ushort4v*)xb,
                                       (BB * SS * DD) / 4);
  transpose_w<<<dim3(32, 32, 4), tb, 0, stream>>>(Wq, Wk, Wv, Wo, wt);
  gemm_qkv<<<1536, 256, 0, stream>>>(xb, wt, qkv, vtb, bq, bv);
  flash_attn<<<1024, 256, 0, stream>>>(qkv, qkv + (size_t)4096 * 1024, vtb, ob);
  gemm_bt<float><<<512, 256, 0, stream>>>(ob, wot, out, bo, 1.0f,
                                          4096, 1024, 1024);
}

// Round 20
// 107.027 us; speedup vs baseline: 1.1518x; 1.0665x over previous
//
#include <hip/hip_runtime.h>
#include <hip/hip_bf16.h>

// Problem constants (Whisper-style MHA): B=2, S=2048, D=1024, H=16, hd=64
#define BB 2
#define SS 2048
#define DD 1024
#define HH 16
#define HD 64
#define QKSCALE 0.35355339059327373f   // 64^-0.25
// 64^-0.25 * sqrt(log2(e)) : folds exp->exp2 domain change into q,k projections
#define QKSCALE_E2 0.42466090144f
#define NEGBIG (-1e9f)

using u16 = unsigned short;
typedef __attribute__((ext_vector_type(8))) short short8;     // 8 bf16 = 4 VGPR
typedef __attribute__((ext_vector_type(4))) float floatx4;    // MFMA acc
typedef __attribute__((ext_vector_type(4))) unsigned short ushort4v;

#define GLOBAL_AS __attribute__((address_space(1)))
#define LDS_AS __attribute__((address_space(3)))

__device__ __forceinline__ u16 f2b(float f) {          // RNE f32->bf16
  union { float f; unsigned u; } v; v.f = f;
  return (u16)((v.u + 0x7fffu + ((v.u >> 16) & 1u)) >> 16);
}

__device__ __forceinline__ u16 bconv(float f) {        // via HW cvt (fuses to cvt_pk)
  union { __hip_bfloat16 h; u16 u; } cv;
  cv.h = __float2bfloat16(f);
  return cv.u;
}

__device__ __forceinline__ float ex2(float f) {        // raw v_exp_f32 (2^x)
  return __builtin_amdgcn_exp2f(f);
}

__device__ __forceinline__ floatx4 vmax4(floatx4 a, floatx4 b) {
  return (floatx4){fmaxf(a[0], b[0]), fmaxf(a[1], b[1]),
                   fmaxf(a[2], b[2]), fmaxf(a[3], b[3])};
}

__device__ __forceinline__ void gload_lds16(const void* g, void* l) {
  __builtin_amdgcn_global_load_lds((GLOBAL_AS void*)(g), (LDS_AS void*)(l), 16, 0, 0);
}

// ---------------- merged prep: x->bf16 convert  +  weight transpose/convert ----------------
// blocks [0,4096): cvt of x (256 thr x 4 f32). blocks [4096,8192): transpose_w tiles.
// Independent outputs (xb vs wt) -> one dispatch lets them overlap instead of serializing.
__global__ __launch_bounds__(256)
void prep(const float* __restrict__ x, ushort4v* __restrict__ xb,
          const float* __restrict__ s0, const float* __restrict__ s1,
          const float* __restrict__ s2, const float* __restrict__ s3,
          u16* __restrict__ wt) {
  const int id = (int)blockIdx.x;
  const int tid = threadIdx.x;
  if (id < 4096) {
    int i = id * 256 + tid;
    const float4* src = (const float4*)x;
    float4 f = src[i];
    ushort4v o = { f2b(f.x), f2b(f.y), f2b(f.z), f2b(f.w) };
    xb[i] = o;
    return;
  }
  __shared__ float tile[32][33];
  const int local = id - 4096;
  const int z = local >> 10;          // weight 0..3
  const int rem = local & 1023;
  const int c0 = (rem & 31) * 32;
  const int r0 = (rem >> 5) * 32;
  const float* src = (z == 0) ? s0 : (z == 1) ? s1 : (z == 2) ? s2 : s3;
  u16* d = wt + (size_t)z * 1024 * 1024;
  const int tx = tid & 31, ty = tid >> 5;   // (32,8)
#pragma unroll
  for (int i = 0; i < 4; ++i)
    tile[ty + i * 8][tx] = src[(size_t)(r0 + ty + i * 8) * 1024 + c0 + tx];
  __syncthreads();
#pragma unroll
  for (int i = 0; i < 4; ++i)
    d[(size_t)(c0 + ty + i * 8) * 1024 + r0 + tx] = f2b(tile[tx][ty + i * 8]);
}

// ------------- out-proj GEMM: 64x128 tile, BK=64, dbuf prefetch, XCD swizzle -------------
template <typename OutT>
__global__ __launch_bounds__(256, 3)
void gemm_bt(const u16* __restrict__ A, const u16* __restrict__ Bt,
             OutT* __restrict__ C, const float* __restrict__ bias,
             float scale, int M, int N, int K) {
  const int tid = threadIdx.x;
  const int lane = tid & 63;
  const int w = tid >> 6;
  const int id = (int)blockIdx.x;
  const int swz = (id & 7) * 64 + (id >> 3);
  const int m0 = (swz & 63) * 64;
  const int n0 = (swz >> 6) * 128;
  __shared__ u16 As[2][64 * 64];     // 8KB per buf
  __shared__ u16 Bs[2][128 * 64];    // 16KB per buf
  floatx4 acc[2][4];
#pragma unroll
  for (int i = 0; i < 2; ++i)
#pragma unroll
    for (int j = 0; j < 4; ++j) acc[i][j] = (floatx4){0.f, 0.f, 0.f, 0.f};

  const int wr = (w >> 1) * 32;
  const int wc = (w & 1) * 64;
  const int g = lane >> 4;
  const int lr = lane & 15;
  const size_t strideA = (size_t)K * 2;

  auto stage = [&](int k0, int buf) {
#pragma unroll
    for (int p = 0; p < 2; ++p) {    // A: 8KB
      int L = tid * 16 + p * 4096;
      int row = L >> 7;
      int cb = (L ^ ((row & 7) << 4)) & 127;
      gload_lds16((const char*)A + (size_t)(m0 + row) * strideA + k0 * 2 + cb,
                  (char*)As[buf] + p * 4096 + w * 1024);
    }
#pragma unroll
    for (int p = 0; p < 4; ++p) {    // B: 16KB
      int L = tid * 16 + p * 4096;
      int row = L >> 7;
      int cb = (L ^ ((row & 7) << 4)) & 127;
      gload_lds16((const char*)Bt + (size_t)(n0 + row) * strideA + k0 * 2 + cb,
                  (char*)Bs[buf] + p * 4096 + w * 1024);
    }
  };

  const int nsteps = K >> 6;
  stage(0, 0);
  for (int t = 0; t < nsteps; ++t) {
    const int buf = t & 1;
    __syncthreads();                       // drains stage(t); guards buf reuse
    if (t + 1 < nsteps) stage((t + 1) << 6, buf ^ 1);
    const u16* as = As[buf];
    const u16* bs = Bs[buf];
#pragma unroll
    for (int ks = 0; ks < 2; ++ks) {
      short8 af[2], bf[4];
      const int c0 = ks * 32 + g * 8;
#pragma unroll
      for (int mi = 0; mi < 2; ++mi) {
        int row = wr + mi * 16 + lr;
        af[mi] = *(const short8*)(as + row * 64 + (c0 ^ ((row & 7) << 3)));
      }
#pragma unroll
      for (int ni = 0; ni < 4; ++ni) {
        int row = wc + ni * 16 + lr;
        bf[ni] = *(const short8*)(bs + row * 64 + (c0 ^ ((row & 7) << 3)));
      }
      __builtin_amdgcn_s_setprio(1);
#pragma unroll
      for (int mi = 0; mi < 2; ++mi)
#pragma unroll
        for (int ni = 0; ni < 4; ++ni)
          acc[mi][ni] = __builtin_amdgcn_mfma_f32_16x16x32_bf16(af[mi], bf[ni],
                                                                acc[mi][ni], 0, 0, 0);
      __builtin_amdgcn_s_setprio(0);
    }
  }
#pragma unroll
  for (int ni = 0; ni < 4; ++ni) {
    int col = n0 + wc + ni * 16 + lr;
    float bvv = bias ? bias[col] : 0.f;
#pragma unroll
    for (int mi = 0; mi < 2; ++mi) {
#pragma unroll
      for (int r = 0; r < 4; ++r) {
        int rowg = m0 + wr + mi * 16 + g * 4 + r;
        float val = (acc[mi][ni][r] + bvv) * scale;
        if constexpr (sizeof(OutT) == 4) C[(size_t)rowg * N + col] = val;
        else C[(size_t)rowg * N + col] = (OutT)f2b(val);
      }
    }
  }
}

// ------------- fused QKV GEMM: 128x128 tile, BK=32 dbuf, XCD swizzle -------------
// (round-17 measured-best: 46us, FETCH 32.8MB)
// seg 0/1 (q,k): coalesced store via per-wave LDS bounce.
// seg 2 (v): direct transposed store into vtb[b*1024+d][s] -> transpose_v eliminated.
__global__ __launch_bounds__(256, 4)
void gemm_qkv(const u16* __restrict__ A, const u16* __restrict__ Wt3,
              u16* __restrict__ Out3, u16* __restrict__ Vt,
              const float* __restrict__ bq, const float* __restrict__ bv) {
  const int id = (int)blockIdx.x;
  const int swz = (id & 7) * 96 + (id >> 3);
  const int bx = swz & 31;
  const int rest = swz >> 5;
  const int by = rest & 7;
  const int seg = rest >> 3;
  const u16* Bt = Wt3 + (size_t)seg * 1024 * 1024;
  u16* C = Out3 + (size_t)seg * 4096 * 1024;
  const float* bias = (seg == 0) ? bq : (seg == 2) ? bv : nullptr;
  const float scale = (seg == 2) ? 1.0f : QKSCALE_E2;   // exp2-domain fold

  const int tid = threadIdx.x;
  const int lane = tid & 63;
  const int w = tid >> 6;
  const int m0 = bx * 128;
  const int n0 = by * 128;
  __shared__ u16 As[2][64 * 64];   // 8KB per buf (128 logical rows x 32 cols, row-paired)
  __shared__ u16 Bs[2][64 * 64];
  floatx4 acc[4][4];
#pragma unroll
  for (int i = 0; i < 4; ++i)
#pragma unroll
    for (int j = 0; j < 4; ++j) acc[i][j] = (floatx4){0.f, 0.f, 0.f, 0.f};
  const int wr = (w >> 1) * 64;
  const int wc = (w & 1) * 64;
  const int g = lane >> 4;
  const int lr = lane & 15;

  auto stage = [&](int k0, int buf) {
#pragma unroll
    for (int p = 0; p < 2; ++p) {
      int L = tid * 16 + p * 4096;
      int lrow = L >> 7;                      // 0..63 LDS row (128B)
      int un = (L & 127) ^ ((lrow & 7) << 4); // un-swizzled intra-row byte
      int r = lrow * 2 + (un >> 6);           // logical row 0..127
      int cb = un & 63;                       // k-byte 0..63 (32 elems)
      gload_lds16((const char*)A + (size_t)(m0 + r) * 2048 + k0 * 2 + cb,
                  (char*)As[buf] + p * 4096 + w * 1024);
      gload_lds16((const char*)Bt + (size_t)(n0 + r) * 2048 + k0 * 2 + cb,
                  (char*)Bs[buf] + p * 4096 + w * 1024);
    }
  };

  stage(0, 0);
  for (int t = 0; t < 32; ++t) {             // 32 K-steps of 32
    const int buf = t & 1;
    __syncthreads();                         // drains stage(t); guards buf reuse
    if (t + 1 < 32) stage((t + 1) << 5, buf ^ 1);
    const u16* as = As[buf];
    const u16* bs = Bs[buf];
    short8 af[4], bf[4];
#pragma unroll
    for (int mi = 0; mi < 4; ++mi) {
      int r = wr + mi * 16 + lr;
      af[mi] = *(const short8*)((const char*)as +
               ((r >> 1) * 128 + ((((r & 1) << 6) | (g * 16)) ^ (((r >> 1) & 7) << 4))));
    }
#pragma unroll
    for (int ni = 0; ni < 4; ++ni) {
      int r = wc + ni * 16 + lr;
      bf[ni] = *(const short8*)((const char*)bs +
               ((r >> 1) * 128 + ((((r & 1) << 6) | (g * 16)) ^ (((r >> 1) & 7) << 4))));
    }
    __builtin_amdgcn_s_setprio(1);
#pragma unroll
    for (int mi = 0; mi < 4; ++mi)
#pragma unroll
      for (int ni = 0; ni < 4; ++ni)
        acc[mi][ni] = __builtin_amdgcn_mfma_f32_16x16x32_bf16(af[mi], bf[ni],
                                                              acc[mi][ni], 0, 0, 0);
    __builtin_amdgcn_s_setprio(0);
  }

  if (seg == 2) {
    // ---- direct V^T epilogue: vtb[bseg*1024 + d][s], 8B stores (4 s-consecutive) ----
    const int bseg = m0 >> 11;                 // batch of this block (tile never straddles)
    const int s0 = (m0 & 2047) + wr + g * 4;   // s base for this lane's rows
#pragma unroll
    for (int ni = 0; ni < 4; ++ni) {
      int d = n0 + wc + ni * 16 + lr;
      float bvv = bv[d];
      u16* vrow = Vt + (size_t)(bseg * 1024 + d) * 2048;
#pragma unroll
      for (int mi = 0; mi < 4; ++mi) {
        ushort4v pk = { f2b(acc[mi][ni][0] + bvv), f2b(acc[mi][ni][1] + bvv),
                        f2b(acc[mi][ni][2] + bvv), f2b(acc[mi][ni][3] + bvv) };
        *(ushort4v*)(vrow + s0 + mi * 16) = pk;
      }
    }
    return;                                    // block-uniform: no barrier divergence
  }

  // ---- coalesced epilogue via per-wave LDS bounce (seg 0/1) ----
  __syncthreads();                            // all K-loop LDS reads done
  u16* eb = (w == 0) ? (u16*)As[0] : (w == 1) ? (u16*)As[1]
          : (w == 2) ? (u16*)Bs[0] : (u16*)Bs[1];   // 8KB per wave; use [16][72]
  const int rr = lane >> 2;                   // 0..15 (row within 16-row strip)
  const int cc = lane & 3;                    // 0..3  (16-col chunk)
  float bv4[4];
#pragma unroll
  for (int ni = 0; ni < 4; ++ni)
    bv4[ni] = bias ? bias[n0 + wc + ni * 16 + lr] : 0.f;
#pragma unroll
  for (int mi = 0; mi < 4; ++mi) {
#pragma unroll
    for (int ni = 0; ni < 4; ++ni)
#pragma unroll
      for (int r = 0; r < 4; ++r)
        eb[(g * 4 + r) * 72 + ni * 16 + lr] =
            f2b((acc[mi][ni][r] + bv4[ni]) * scale);
    short8 v0 = *(const short8*)(eb + rr * 72 + cc * 16);
    short8 v1 = *(const short8*)(eb + rr * 72 + cc * 16 + 8);
    u16* dst = C + (size_t)(m0 + wr + mi * 16 + rr) * 1024 + n0 + wc + cc * 16;
    *(short8*)dst = v0;
    *(short8*)(dst + 8) = v1;
  }
}

// ------------- flash attention: swapped-QK (S^T), single stream, 1 q-tile/block -------------
// (settled round-10 structure: P via LDS, 40KB, 4 blocks/CU, balanced qt mapping — frozen)
__device__ __forceinline__ void stream_softmax(floatx4 (&sa)[4], float& m, float& l,
                                               floatx4 (&acc)[4], u16* pl,
                                               bool diag, int wlr, int g, int lr) {
  if (diag) {
#pragma unroll
    for (int ct = 0; ct < 4; ++ct)
#pragma unroll
      for (int r = 0; r < 4; ++r)
        if (ct * 16 + g * 4 + r > wlr) sa[ct][r] += NEGBIG;
  }
  floatx4 v = vmax4(vmax4(sa[0], sa[1]), vmax4(sa[2], sa[3]));
  float mx = fmaxf(fmaxf(v[0], v[1]), fmaxf(v[2], v[3]));
  mx = fmaxf(mx, __shfl_xor(mx, 16, 64));
  mx = fmaxf(mx, __shfl_xor(mx, 32, 64));
  if (!__all(mx <= m + 8.f)) {
    float mn = fmaxf(m, mx);
    float al = ex2(m - mn);
    l *= al;
#pragma unroll
    for (int dt = 0; dt < 4; ++dt) acc[dt] *= al;
    m = mn;
  }
  floatx4 p[4];
#pragma unroll
  for (int ct = 0; ct < 4; ++ct)
#pragma unroll
    for (int r = 0; r < 4; ++r)
      p[ct][r] = ex2(sa[ct][r] - m);
  floatx4 s = (p[0] + p[1]) + (p[2] + p[3]);
  float rs = (s[0] + s[1]) + (s[2] + s[3]);
  rs += __shfl_xor(rs, 16, 64);
  rs += __shfl_xor(rs, 32, 64);
  l += rs;
#pragma unroll
  for (int ct = 0; ct < 4; ++ct) {
    ushort4v pk = { bconv(p[ct][0]), bconv(p[ct][1]),
                    bconv(p[ct][2]), bconv(p[ct][3]) };
    *(ushort4v*)((char*)pl + ((lr * 128 + ct * 32 + g * 8) ^ ((lr & 7) << 4))) = pk;
  }
}

__global__ __launch_bounds__(256, 4)
void flash_attn(const u16* __restrict__ q, const u16* __restrict__ k,
                const u16* __restrict__ vt, u16* __restrict__ o) {
  const int tid = threadIdx.x;
  const int lane = tid & 63;
  const int w = tid >> 6;
  const int g = lane >> 4;
  const int lr = lane & 15;
  const int i = (int)blockIdx.x;      // 0..1023
  const int x = i & 7;
  const int kk = i >> 3;              // 0..127
  const int s = kk & 3;
  const int mI = kk >> 2;             // 0..31
  const int u = mI >> 3;
  const int v = mI & 7;
  const int gg = x * 4 + s;           // (b,h), 4 groups per XCD stream
  const int b = gg >> 4;
  const int h = gg & 15;
  const int a = (u + s) & 3;
  const int qt = (a == 0) ? v : (a == 1) ? (31 - v) : (a == 2) ? (16 + v) : (15 - v);
  const int row0 = qt * 64 + w * 16;
  const int wlr = w * 16 + lr;

  __shared__ u16 Ks[2][64 * 64];      // 16KB
  __shared__ u16 Vs[2][64 * 64];      // 16KB
  __shared__ u16 Pl[4][16 * 64];      // 8KB

  short8 qf[2];
  {
    const u16* qp = q + (size_t)(b * SS + row0 + lr) * DD + h * HD + g * 8;
    qf[0] = *(const short8*)qp;
    qf[1] = *(const short8*)(qp + 32);
  }
  floatx4 acc[4];
#pragma unroll
  for (int dt = 0; dt < 4; ++dt) acc[dt] = (floatx4){0.f, 0.f, 0.f, 0.f};
  float m = -1e30f, l = 0.f;

  const char* kbase = (const char*)(k + (size_t)(b * SS) * DD + h * HD);
  const char* vbase = (const char*)(vt + (size_t)((b * HH + h) * HD) * SS);
  const int nt = qt + 1;

  auto stage = [&](int t, int buf) {
    const int kvb = t * 64;
#pragma unroll
    for (int p = 0; p < 2; ++p) {
      int L = tid * 16 + p * 4096;
      int row = L >> 7;
      int cb = (L ^ ((row & 7) << 4)) & 127;
      gload_lds16(kbase + (size_t)(kvb + row) * (DD * 2) + cb,
                  (char*)Ks + buf * 8192 + p * 4096 + w * 1024);
      gload_lds16(vbase + (size_t)row * (SS * 2) + kvb * 2 + cb,
                  (char*)Vs + buf * 8192 + p * 4096 + w * 1024);
    }
  };

  stage(0, 0);
  int cur = 0;
  for (int t = 0; t < nt; ++t) {
    __syncthreads();
    if (t + 1 < nt) stage(t + 1, cur ^ 1);
    const u16* kc = Ks[cur];
    const u16* vc = Vs[cur];

    floatx4 sa[4];
#pragma unroll
    for (int ct = 0; ct < 4; ++ct) sa[ct] = (floatx4){0.f, 0.f, 0.f, 0.f};
    __builtin_amdgcn_s_setprio(1);
#pragma unroll
    for (int ks = 0; ks < 2; ++ks) {
      const int c0 = ks * 32 + g * 8;
#pragma unroll
      for (int ct = 0; ct < 4; ++ct) {
        int row = ct * 16 + lr;
        short8 kf = *(const short8*)(kc + row * 64 + (c0 ^ ((row & 7) << 3)));
        sa[ct] = __builtin_amdgcn_mfma_f32_16x16x32_bf16(kf, qf[ks], sa[ct], 0, 0, 0);
      }
    }
    __builtin_amdgcn_s_setprio(0);

    stream_softmax(sa, m, l, acc, Pl[w], t == qt, wlr, g, lr);

    __builtin_amdgcn_s_setprio(1);
#pragma unroll
    for (int ks = 0; ks < 2; ++ks) {
      const int c0 = ks * 32 + g * 8;
      int pby = (lr * 128 + ks * 64 + g * 16) ^ ((lr & 7) << 4);
      short8 pf = *(const short8*)((const char*)Pl[w] + pby);
#pragma unroll
      for (int dt = 0; dt < 4; ++dt) {
        int row = dt * 16 + lr;
        short8 vf = *(const short8*)(vc + row * 64 + (c0 ^ ((row & 7) << 3)));
        acc[dt] = __builtin_amdgcn_mfma_f32_16x16x32_bf16(vf, pf, acc[dt], 0, 0, 0);
      }
    }
    __builtin_amdgcn_s_setprio(0);
    cur ^= 1;
  }

  float inv = 1.0f / l;
#pragma unroll
  for (int dt = 0; dt < 4; ++dt) {
    ushort4v pa = { bconv(acc[dt][0] * inv), bconv(acc[dt][1] * inv),
                    bconv(acc[dt][2] * inv), bconv(acc[dt][3] * inv) };
    *(ushort4v*)(o + (size_t)(b * SS + row0 + lr) * DD + h * HD + dt * 16 + g * 4) = pa;
  }
}

extern "C" void kernel_launch(void* const* d_in, const int* in_sizes, int n_in,
                              void* d_out, int out_size, void* d_ws, size_t ws_size,
                              hipStream_t stream) {
  const float* x  = (const float*)d_in[0];
  // d_in[1] = mask: causal additive -1e9, replicated analytically in-kernel
  const float* Wq = (const float*)d_in[2];
  const float* bq = (const float*)d_in[3];
  const float* Wk = (const float*)d_in[4];
  const float* Wv = (const float*)d_in[5];
  const float* bv = (const float*)d_in[6];
  const float* Wo = (const float*)d_in[7];
  const float* bo = (const float*)d_in[8];
  float* out = (float*)d_out;

  char* ws = (char*)d_ws;
  u16* xb  = (u16*)(ws);                    // 8MB  x bf16 [4096][1024]
  u16* wt  = (u16*)(ws + (8u << 20));       // 8MB  Wq^T,Wk^T,Wv^T,Wo^T bf16
  u16* qkv = (u16*)(ws + (16u << 20));      // q,k bf16 [4096][1024] (v slab unused)
  u16* vtb = (u16*)(ws + (40u << 20));      // 8MB  v^T per batch [B*D][S] (written by qkv)
  u16* ob  = (u16*)(ws + (48u << 20));      // 8MB  attn out bf16
  u16* wot = wt + 3u * 1024 * 1024;

  prep<<<8192, 256, 0, stream>>>(x, (ushort4v*)xb, Wq, Wk, Wv, Wo, wt);
  gemm_qkv<<<768, 256, 0, stream>>>(xb, wt, qkv, vtb, bq, bv);
  flash_attn<<<1024, 256, 0, stream>>>(qkv, qkv + (size_t)4096 * 1024, vtb, ob);
  gemm_bt<float><<<512, 256, 0, stream>>>(ob, wot, out, bo, 1.0f,
                                          4096, 1024, 1024);
}